// Round 7
// baseline (422.669 us; speedup 1.0000x reference)
//
#include <hip/hip_runtime.h>

#define B_  4
#define S_  2048
#define D_  1024
#define H_  16
#define DH_ 64

typedef __attribute__((ext_vector_type(8)))  short bf16x8;
typedef __attribute__((ext_vector_type(4)))  float f32x4;
typedef __attribute__((ext_vector_type(16))) float f32x16;
typedef __attribute__((ext_vector_type(8)))  unsigned short u16x8;
typedef __attribute__((ext_vector_type(4)))  unsigned int u32x4;

__device__ __forceinline__ unsigned short f2bf(float x) {
    unsigned int u = __builtin_bit_cast(unsigned int, x);
    u += 0x7fffu + ((u >> 16) & 1u);            // round-to-nearest-even
    return (unsigned short)(u >> 16);
}

__device__ __forceinline__ float fexp2(float x) {
#if __has_builtin(__builtin_amdgcn_exp2f)
    return __builtin_amdgcn_exp2f(x);
#else
    return exp2f(x);
#endif
}

__device__ __forceinline__ unsigned int cvtpk(float lo, float hi) {
    unsigned int r;
    asm("v_cvt_pk_bf16_f32 %0, %1, %2" : "=v"(r) : "v"(lo), "v"(hi));
    return r;
}

// async global->LDS, 16B per lane
__device__ __forceinline__ void cp16(const void* g, void* l) {
    typedef const __attribute__((address_space(1))) unsigned int* gp_t;
    typedef __attribute__((address_space(3))) unsigned int* lp_t;
    __builtin_amdgcn_global_load_lds((gp_t)(unsigned long long)(size_t)g,
                                     (lp_t)(unsigned int)(size_t)l, 16, 0, 0);
}

// ---------------------------------------------------------------- converts
__global__ __launch_bounds__(256)
void conv_x(const float* __restrict__ x, unsigned short* __restrict__ xs)
{
    int gid = blockIdx.x * 256 + threadIdx.x;
    int row = gid >> 7;
    int rem = gid & 127;
    int blk = rem >> 3;
    int c   = rem & 7;
    const float* src = x + (size_t)row * 1024 + blk * 64 + c * 8;
    float4 a = *(const float4*)src;
    float4 b = *(const float4*)(src + 4);
    u16x8 v;
    v[0] = f2bf(a.x); v[1] = f2bf(a.y); v[2] = f2bf(a.z); v[3] = f2bf(a.w);
    v[4] = f2bf(b.x); v[5] = f2bf(b.y); v[6] = f2bf(b.z); v[7] = f2bf(b.w);
    *(u16x8*)(xs + (size_t)row * 1024 + blk * 64 + ((c ^ (row & 7)) * 8)) = v;
}

// Q's weights pre-scaled by (1/sqrt(DH)) * log2(e) -> attn works in exp2 domain.
__global__ __launch_bounds__(256)
void conv_wqkv(const float* __restrict__ Wq, const float* __restrict__ Wk,
               const float* __restrict__ Wv, unsigned short* __restrict__ Wt)
{
    __shared__ float Wl[64][65];
    const int tid = threadIdx.x;
    const int kt  = blockIdx.x;
    const int y   = blockIdx.y;
    const int mat = y >> 4, h = y & 15;
    const float* W = (mat == 0 ? Wq : (mat == 1 ? Wk : Wv)) + (size_t)h * 1024 * 64;
    const float sc = (mat == 0) ? 0.125f * 1.4426950408889634f : 1.0f;
    #pragma unroll
    for (int i = 0; i < 4; ++i) {
        int idx = tid + i * 256;
        int kk = idx >> 4, c4 = (idx & 15) * 4;
        *(float4*)&Wl[kk][c4] = *(const float4*)&W[(size_t)(kt * 64 + kk) * 64 + c4];
    }
    __syncthreads();
    #pragma unroll
    for (int i = 0; i < 2; ++i) {
        int cid = tid + i * 256;
        int c = cid >> 3, kc = cid & 7;
        u16x8 v;
        #pragma unroll
        for (int j = 0; j < 8; ++j) v[j] = f2bf(Wl[kc * 8 + j][c] * sc);
        *(u16x8*)(Wt + ((size_t)y * 64 + c) * 1024 + kt * 64 + ((kc ^ (c & 7)) * 8)) = v;
    }
}

__global__ __launch_bounds__(256)
void conv_wo(const float* __restrict__ Wo, unsigned short* __restrict__ Wot)
{
    __shared__ float Wl[64][65];
    const int tid = threadIdx.x;
    const int kt = blockIdx.x, ct = blockIdx.y;
    #pragma unroll
    for (int i = 0; i < 4; ++i) {
        int idx = tid + i * 256;
        int kk = idx >> 4, c4 = (idx & 15) * 4;
        *(float4*)&Wl[kk][c4] = *(const float4*)&Wo[(size_t)(kt * 64 + kk) * 1024 + ct * 64 + c4];
    }
    __syncthreads();
    #pragma unroll
    for (int i = 0; i < 2; ++i) {
        int cid = tid + i * 256;
        int c = cid >> 3, kc = cid & 7;
        u16x8 v;
        #pragma unroll
        for (int j = 0; j < 8; ++j) v[j] = f2bf(Wl[kc * 8 + j][c]);
        *(u16x8*)(Wot + (size_t)(ct * 64 + c) * 1024 + kt * 64 + ((kc ^ (c & 7)) * 8)) = v;
    }
}

// ------------------------------------------------------------ QKV MFMA GEMM
// V is written TRANSPOSED per (b,h): [64 d][2048 s], via LDS transpose.
__global__ __launch_bounds__(256, 2)
void qkv_mfma(const unsigned short* __restrict__ Xs,
              const unsigned short* __restrict__ Wt,
              unsigned short* __restrict__ Qo,
              unsigned short* __restrict__ Ko,
              unsigned short* __restrict__ Vo)
{
    __shared__ __align__(16) unsigned short As[2][128 * 64];
    __shared__ __align__(16) unsigned short Bs[2][64 * 64];

    const int tid  = threadIdx.x;
    const int wid  = tid >> 6;
    const int lane = tid & 63;
    const int lg   = lane >> 4;
    const int lr   = lane & 15;
    const int row0 = blockIdx.x * 128;
    const int y    = blockIdx.y;
    const int mat  = y >> 4;
    const int h    = y & 15;

    const unsigned short* Wh = Wt + (size_t)y * (64 * 1024);
    unsigned short* Out = (mat == 0 ? Qo : (mat == 1 ? Ko : Vo)) + (size_t)h * S_ * DH_;

    const int sr = tid >> 3;
    const int sc = tid & 7;

    f32x4 acc[2][4];
    #pragma unroll
    for (int rb = 0; rb < 2; ++rb)
        #pragma unroll
        for (int nb = 0; nb < 4; ++nb) acc[rb][nb] = (f32x4)(0.f);

    #pragma unroll
    for (int i = 0; i < 4; ++i)
        cp16(Xs + (size_t)(row0 + sr + i * 32) * 1024 + sc * 8, &As[0][(tid + i * 256) * 8]);
    #pragma unroll
    for (int i = 0; i < 2; ++i)
        cp16(Wh + (size_t)(sr + i * 32) * 1024 + sc * 8, &Bs[0][(tid + i * 256) * 8]);
    asm volatile("s_waitcnt vmcnt(0)" ::: "memory");
    __syncthreads();

    int cur = 0;
    for (int kt = 0; kt < 16; ++kt) {
        if (kt < 15) {
            const int kb = (kt + 1) * 64;
            #pragma unroll
            for (int i = 0; i < 4; ++i)
                cp16(Xs + (size_t)(row0 + sr + i * 32) * 1024 + kb + sc * 8,
                     &As[cur ^ 1][(tid + i * 256) * 8]);
            #pragma unroll
            for (int i = 0; i < 2; ++i)
                cp16(Wh + (size_t)(sr + i * 32) * 1024 + kb + sc * 8,
                     &Bs[cur ^ 1][(tid + i * 256) * 8]);
        }
        bf16x8 af[2][2], bfr[4][2];
        #pragma unroll
        for (int c = 0; c < 2; ++c) {
            #pragma unroll
            for (int rb = 0; rb < 2; ++rb) {
                int row = wid * 32 + rb * 16 + lr;
                int chk = (c * 4 + lg) ^ (row & 7);
                af[rb][c] = *(const bf16x8*)&As[cur][row * 64 + chk * 8];
            }
            #pragma unroll
            for (int nb = 0; nb < 4; ++nb) {
                int brow = nb * 16 + lr;
                int chk = (c * 4 + lg) ^ (brow & 7);
                bfr[nb][c] = *(const bf16x8*)&Bs[cur][brow * 64 + chk * 8];
            }
        }
        #pragma unroll
        for (int c = 0; c < 2; ++c)
            #pragma unroll
            for (int nb = 0; nb < 4; ++nb)
                #pragma unroll
                for (int rb = 0; rb < 2; ++rb)
                    acc[rb][nb] = __builtin_amdgcn_mfma_f32_16x16x32_bf16(
                        af[rb][c], bfr[nb][c], acc[rb][nb], 0, 0, 0);
        asm volatile("s_waitcnt vmcnt(0)" ::: "memory");
        __syncthreads();
        cur ^= 1;
    }

    if (mat == 2) {
        // transpose 128s x 64d -> V^T [bh][d][s] via LDS (reuse As, pitch 132)
        unsigned short* T = (unsigned short*)&As[0][0];
        #pragma unroll
        for (int rb = 0; rb < 2; ++rb)
            #pragma unroll
            for (int r = 0; r < 4; ++r) {
                int sl = wid * 32 + rb * 16 + lg * 4 + r;
                #pragma unroll
                for (int nb = 0; nb < 4; ++nb)
                    T[(nb * 16 + lr) * 132 + sl] = f2bf(acc[rb][nb][r]);
            }
        __syncthreads();
        // FIX(r5): include the batch offset. All 128 rows of this block
        // belong to one batch: b = row0>>11, s0 = row0&2047.
        const int bb = row0 >> 11;
        const int s0 = row0 & (S_ - 1);
        unsigned short* OutT = Vo + ((size_t)bb * H_ + h) * DH_ * S_;
        int d = tid >> 2, s4 = (tid & 3) * 32;
        #pragma unroll
        for (int i = 0; i < 4; ++i) {
            u16x8 v = *(const u16x8*)&T[d * 132 + s4 + i * 8];
            *(u16x8*)(OutT + (size_t)d * S_ + s0 + s4 + i * 8) = v;
        }
    } else {
        #pragma unroll
        for (int rb = 0; rb < 2; ++rb)
            #pragma unroll
            for (int r = 0; r < 4; ++r) {
                int row = row0 + wid * 32 + rb * 16 + lg * 4 + r;
                int b = row >> 11, s = row & (S_ - 1);
                size_t base = (size_t)b * H_ * S_ * DH_ + (size_t)s * DH_;
                #pragma unroll
                for (int nb = 0; nb < 4; ++nb)
                    Out[base + nb * 16 + lr] = f2bf(acc[rb][nb][r]);
            }
    }
}

// --------------------------------------------- flash attention, barrier-free
// 4 waves/block, lane owns q-row (lane&31). KV tile 64 keys. K and V^T read
// straight from global (L2-resident; XCD-chunked block swizzle keeps each
// (b,h)'s working set on one XCD's L2). P packed in-reg (cvt_pk + shfl32).
// No LDS, no barriers in the main loop.
__global__ __launch_bounds__(256, 2)
void attn_kernel(const unsigned short* __restrict__ Q,
                 const unsigned short* __restrict__ K,
                 const unsigned short* __restrict__ Vt,   // [bh][64 d][2048 s]
                 unsigned short* __restrict__ Cs)
{
    __shared__ __align__(16) unsigned short Olds[4][32 * 72];

    const int tid  = threadIdx.x;
    const int wid  = tid >> 6;
    const int lane = tid & 63;
    const int h    = lane >> 5;     // lane half
    const int q31  = lane & 31;     // this lane's q-row
    // XCD-chunked decode: all 16 q-blocks of one bh share id%8 -> same XCD
    const int id   = blockIdx.x;          // 0..1023
    const int bh   = (id & 7) * 8 + (id >> 7);
    const int qx   = (id >> 3) & 15;
    const int b    = bh >> 4;
    const int hh   = bh & 15;
    const int q0   = qx * 128;
    const int qrow = q0 + wid * 32 + q31;

    const unsigned short* Qbh = Q  + (size_t)bh * S_ * DH_;
    const unsigned short* Kbh = K  + (size_t)bh * S_ * DH_;
    const unsigned short* Vbh = Vt + (size_t)bh * DH_ * S_;

    bf16x8 qf[4];
    #pragma unroll
    for (int dc = 0; dc < 4; ++dc)
        qf[dc] = *(const bf16x8*)(Qbh + (size_t)qrow * DH_ + dc * 16 + h * 8);

    f32x16 oacc[2];
    oacc[0] = (f32x16)0.f;
    oacc[1] = (f32x16)0.f;
    float m = -1e30f, lsum = 0.f;

    for (int kt = 0; kt < S_ / 64; ++kt) {
        // ---- issue V^T fragment loads first (consumed last, by PV) ----
        bf16x8 vf[4][2];
        #pragma unroll
        for (int kB = 0; kB < 4; ++kB)
            #pragma unroll
            for (int dh = 0; dh < 2; ++dh)
                vf[kB][dh] = *(const bf16x8*)(Vbh + (size_t)(dh * 32 + q31) * S_
                                              + kt * 64 + (kB * 2 + h) * 8);

        // ---- S^T = K Q^T: D rows = key, cols = q (lane&31) ----
        f32x16 sf[2];
        #pragma unroll
        for (int kb = 0; kb < 2; ++kb) {
            bf16x8 kf[4];
            #pragma unroll
            for (int dc = 0; dc < 4; ++dc)
                kf[dc] = *(const bf16x8*)(Kbh + (size_t)(kt * 64 + kb * 32 + q31) * DH_ + dc * 16 + h * 8);
            f32x16 s = (f32x16)0.f;
            #pragma unroll
            for (int dc = 0; dc < 4; ++dc)
                s = __builtin_amdgcn_mfma_f32_32x32x16_bf16(kf[dc], qf[dc], s, 0, 0, 0);
            sf[kb] = s;
        }

        // ---- lane-local online softmax (exp2 domain; defer-max THR=8) ----
        float mx = -1e30f;
        #pragma unroll
        for (int kb = 0; kb < 2; ++kb)
            #pragma unroll
            for (int r = 0; r < 16; r += 4)
                mx = fmaxf(mx, fmaxf(fmaxf(sf[kb][r], sf[kb][r + 1]),
                                     fmaxf(sf[kb][r + 2], sf[kb][r + 3])));
        mx = fmaxf(mx, __shfl_xor(mx, 32));
        if (!__all(mx <= m + 8.f)) {
            float mnew = fmaxf(m, mx);
            float a = fexp2(m - mnew);
            m = mnew;
            lsum *= a;
            oacc[0] *= a;
            oacc[1] *= a;
        }
        float p0 = 0.f, p1 = 0.f, p2 = 0.f, p3 = 0.f;
        #pragma unroll
        for (int kb = 0; kb < 2; ++kb)
            #pragma unroll
            for (int r = 0; r < 16; r += 4) {
                float e0 = fexp2(sf[kb][r]     - m);
                float e1 = fexp2(sf[kb][r + 1] - m);
                float e2 = fexp2(sf[kb][r + 2] - m);
                float e3 = fexp2(sf[kb][r + 3] - m);
                sf[kb][r] = e0; sf[kb][r + 1] = e1; sf[kb][r + 2] = e2; sf[kb][r + 3] = e3;
                p0 += e0; p1 += e1; p2 += e2; p3 += e3;
            }
        float ps = (p0 + p1) + (p2 + p3);
        ps += __shfl_xor(ps, 32);
        lsum += ps;

        // ---- pack P to bf16 pairs; exchange lane halves ----
        // own[kb][j] covers keys kb*32 + 8*(j>>1) + 4*h + 2*(j&1) + {0,1}
        unsigned int own[2][8], swp[2][8];
        #pragma unroll
        for (int kb = 0; kb < 2; ++kb)
            #pragma unroll
            for (int j = 0; j < 8; ++j)
                own[kb][j] = cvtpk(sf[kb][2 * j], sf[kb][2 * j + 1]);
        #pragma unroll
        for (int kb = 0; kb < 2; ++kb)
            #pragma unroll
            for (int j = 0; j < 8; ++j)
                swp[kb][j] = (unsigned int)__shfl_xor((int)own[kb][j], 32);

        // ---- O^T += V^T P^T: D rows = d, cols = q ----
        #pragma unroll
        for (int kB = 0; kB < 4; ++kB) {
            const int kb = kB >> 1;
            const int J  = (kB & 1) * 4;
            unsigned int b0 = h ? swp[kb][J + 2] : own[kb][J + 0];
            unsigned int b1 = h ? swp[kb][J + 3] : own[kb][J + 1];
            unsigned int b2 = h ? own[kb][J + 2] : swp[kb][J + 0];
            unsigned int b3 = h ? own[kb][J + 3] : swp[kb][J + 1];
            u32x4 pw = {b0, b1, b2, b3};
            bf16x8 pb = __builtin_bit_cast(bf16x8, pw);
            #pragma unroll
            for (int dh = 0; dh < 2; ++dh)
                oacc[dh] = __builtin_amdgcn_mfma_f32_32x32x16_bf16(vf[kB][dh], pb, oacc[dh], 0, 0, 0);
        }
    }

    // ---- epilogue: normalize, transpose via per-wave LDS, swizzled stores ----
    float inv = 1.f / lsum;
    #pragma unroll
    for (int dh = 0; dh < 2; ++dh)
        #pragma unroll
        for (int r = 0; r < 16; ++r) {
            int d = dh * 32 + (r & 3) + ((r >> 2) << 3) + h * 4;
            Olds[wid][q31 * 72 + d] = f2bf(oacc[dh][r] * inv);
        }
    __syncthreads();
    const int orow = lane >> 1;
    const int srow = q0 + wid * 32 + orow;
    unsigned short* gout = Cs + ((size_t)b * S_ + srow) * 1024 + hh * 64;
    #pragma unroll
    for (int c = 0; c < 4; ++c) {
        int ch  = (lane & 1) * 4 + c;
        int chs = ch ^ (srow & 7);
        u16x8 v = *(const u16x8*)&Olds[wid][orow * 72 + ch * 8];
        *(u16x8*)(gout + chs * 8) = v;
    }
}

// ---------------------------------------------------------- output proj MFMA
__global__ __launch_bounds__(256, 2)
void oproj_mfma(const unsigned short* __restrict__ Cs,
                const unsigned short* __restrict__ Wot,
                const float* __restrict__ bo,
                float* __restrict__ out)
{
    __shared__ __align__(16) unsigned short As[2][128 * 64];
    __shared__ __align__(16) unsigned short Bs[2][64 * 64];

    const int tid  = threadIdx.x;
    const int wid  = tid >> 6;
    const int lane = tid & 63;
    const int lg   = lane >> 4;
    const int lr   = lane & 15;
    const int row0 = blockIdx.x * 128;
    const int col0 = blockIdx.y * 64;

    const int sr = tid >> 3;
    const int sc = tid & 7;

    f32x4 acc[2][4];
    #pragma unroll
    for (int rb = 0; rb < 2; ++rb)
        #pragma unroll
        for (int nb = 0; nb < 4; ++nb) acc[rb][nb] = (f32x4)(0.f);

    #pragma unroll
    for (int i = 0; i < 4; ++i)
        cp16(Cs + (size_t)(row0 + sr + i * 32) * 1024 + sc * 8, &As[0][(tid + i * 256) * 8]);
    #pragma unroll
    for (int i = 0; i < 2; ++i)
        cp16(Wot + (size_t)(col0 + sr + i * 32) * 1024 + sc * 8, &Bs[0][(tid + i * 256) * 8]);
    asm volatile("s_waitcnt vmcnt(0)" ::: "memory");
    __syncthreads();

    int cur = 0;
    for (int kt = 0; kt < 16; ++kt) {
        if (kt < 15) {
            const int kb = (kt + 1) * 64;
            #pragma unroll
            for (int i = 0; i < 4; ++i)
                cp16(Cs + (size_t)(row0 + sr + i * 32) * 1024 + kb + sc * 8,
                     &As[cur ^ 1][(tid + i * 256) * 8]);
            #pragma unroll
            for (int i = 0; i < 2; ++i)
                cp16(Wot + (size_t)(col0 + sr + i * 32) * 1024 + kb + sc * 8,
                     &Bs[cur ^ 1][(tid + i * 256) * 8]);
        }
        bf16x8 af[2][2], bfr[4][2];
        #pragma unroll
        for (int c = 0; c < 2; ++c) {
            #pragma unroll
            for (int rb = 0; rb < 2; ++rb) {
                int row = wid * 32 + rb * 16 + lr;
                int chk = (c * 4 + lg) ^ (row & 7);
                af[rb][c] = *(const bf16x8*)&As[cur][row * 64 + chk * 8];
            }
            #pragma unroll
            for (int nb = 0; nb < 4; ++nb) {
                int brow = nb * 16 + lr;
                int chk = (c * 4 + lg) ^ (brow & 7);
                bfr[nb][c] = *(const bf16x8*)&Bs[cur][brow * 64 + chk * 8];
            }
        }
        #pragma unroll
        for (int c = 0; c < 2; ++c)
            #pragma unroll
            for (int nb = 0; nb < 4; ++nb)
                #pragma unroll
                for (int rb = 0; rb < 2; ++rb)
                    acc[rb][nb] = __builtin_amdgcn_mfma_f32_16x16x32_bf16(
                        af[rb][c], bfr[nb][c], acc[rb][nb], 0, 0, 0);
        asm volatile("s_waitcnt vmcnt(0)" ::: "memory");
        __syncthreads();
        cur ^= 1;
    }

    float bb[4];
    #pragma unroll
    for (int nb = 0; nb < 4; ++nb) bb[nb] = bo[col0 + nb * 16 + lr];
    #pragma unroll
    for (int rb = 0; rb < 2; ++rb)
        #pragma unroll
        for (int r = 0; r < 4; ++r) {
            int row = row0 + wid * 32 + rb * 16 + lg * 4 + r;
            #pragma unroll
            for (int nb = 0; nb < 4; ++nb)
                out[(size_t)row * 1024 + col0 + nb * 16 + lr] = acc[rb][nb][r] + bb[nb];
        }
}

extern "C" void kernel_launch(void* const* d_in, const int* in_sizes, int n_in,
                              void* d_out, int out_size, void* d_ws, size_t ws_size,
                              hipStream_t stream) {
    const float* x  = (const float*)d_in[0];
    const float* Wq = (const float*)d_in[1];
    const float* Wk = (const float*)d_in[2];
    const float* Wv = (const float*)d_in[3];
    const float* Wo = (const float*)d_in[4];
    const float* bo = (const float*)d_in[5];
    float* out = (float*)d_out;

    const size_t perQ = (size_t)B_ * H_ * S_ * DH_;
    unsigned short* xs  = (unsigned short*)d_ws;
    unsigned short* Wt  = xs + (size_t)8192 * 1024;
    unsigned short* Wot = Wt + (size_t)48 * 64 * 1024;
    unsigned short* Qb  = Wot + (size_t)1024 * 1024;
    unsigned short* Kb  = Qb + perQ;
    unsigned short* Vb  = Kb + perQ;                       // V^T [bh][64][2048]
    unsigned short* Cb  = Vb + perQ;

    conv_x<<<4096, 256, 0, stream>>>(x, xs);
    conv_wqkv<<<dim3(16, 48), 256, 0, stream>>>(Wq, Wk, Wv, Wt);
    conv_wo<<<dim3(16, 16), 256, 0, stream>>>(Wo, Wot);
    qkv_mfma<<<dim3(64, 48), 256, 0, stream>>>(xs, Wt, Qb, Kb, Vb);
    attn_kernel<<<1024, 256, 0, stream>>>(Qb, Kb, Vb, Cb);
    oproj_mfma<<<dim3(64, 16), 256, 0, stream>>>(Cb, Wot, bo, out);
}

// Round 8
// 289.827 us; speedup vs baseline: 1.4583x; 1.4583x over previous
//
#include <hip/hip_runtime.h>

#define B_  4
#define S_  2048
#define D_  1024
#define H_  16
#define DH_ 64

typedef __attribute__((ext_vector_type(8)))  short bf16x8;
typedef __attribute__((ext_vector_type(4)))  float f32x4;
typedef __attribute__((ext_vector_type(16))) float f32x16;
typedef __attribute__((ext_vector_type(8)))  unsigned short u16x8;
typedef __attribute__((ext_vector_type(4)))  unsigned int u32x4;

__device__ __forceinline__ unsigned short f2bf(float x) {
    unsigned int u = __builtin_bit_cast(unsigned int, x);
    u += 0x7fffu + ((u >> 16) & 1u);            // round-to-nearest-even
    return (unsigned short)(u >> 16);
}

__device__ __forceinline__ float fexp2(float x) {
#if __has_builtin(__builtin_amdgcn_exp2f)
    return __builtin_amdgcn_exp2f(x);
#else
    return exp2f(x);
#endif
}

__device__ __forceinline__ unsigned int cvtpk(float lo, float hi) {
    unsigned int r;
    asm("v_cvt_pk_bf16_f32 %0, %1, %2" : "=v"(r) : "v"(lo), "v"(hi));
    return r;
}

// async global->LDS, 16B per lane
__device__ __forceinline__ void cp16(const void* g, void* l) {
    typedef const __attribute__((address_space(1))) unsigned int* gp_t;
    typedef __attribute__((address_space(3))) unsigned int* lp_t;
    __builtin_amdgcn_global_load_lds((gp_t)(unsigned long long)(size_t)g,
                                     (lp_t)(unsigned int)(size_t)l, 16, 0, 0);
}

// ---------------------------------------------------------------- converts
__global__ __launch_bounds__(256)
void conv_x(const float* __restrict__ x, unsigned short* __restrict__ xs)
{
    int gid = blockIdx.x * 256 + threadIdx.x;
    int row = gid >> 7;
    int rem = gid & 127;
    int blk = rem >> 3;
    int c   = rem & 7;
    const float* src = x + (size_t)row * 1024 + blk * 64 + c * 8;
    float4 a = *(const float4*)src;
    float4 b = *(const float4*)(src + 4);
    u16x8 v;
    v[0] = f2bf(a.x); v[1] = f2bf(a.y); v[2] = f2bf(a.z); v[3] = f2bf(a.w);
    v[4] = f2bf(b.x); v[5] = f2bf(b.y); v[6] = f2bf(b.z); v[7] = f2bf(b.w);
    *(u16x8*)(xs + (size_t)row * 1024 + blk * 64 + ((c ^ (row & 7)) * 8)) = v;
}

// Q's weights pre-scaled by (1/sqrt(DH)) * log2(e) -> attn works in exp2 domain.
__global__ __launch_bounds__(256)
void conv_wqkv(const float* __restrict__ Wq, const float* __restrict__ Wk,
               const float* __restrict__ Wv, unsigned short* __restrict__ Wt)
{
    __shared__ float Wl[64][65];
    const int tid = threadIdx.x;
    const int kt  = blockIdx.x;
    const int y   = blockIdx.y;
    const int mat = y >> 4, h = y & 15;
    const float* W = (mat == 0 ? Wq : (mat == 1 ? Wk : Wv)) + (size_t)h * 1024 * 64;
    const float sc = (mat == 0) ? 0.125f * 1.4426950408889634f : 1.0f;
    #pragma unroll
    for (int i = 0; i < 4; ++i) {
        int idx = tid + i * 256;
        int kk = idx >> 4, c4 = (idx & 15) * 4;
        *(float4*)&Wl[kk][c4] = *(const float4*)&W[(size_t)(kt * 64 + kk) * 64 + c4];
    }
    __syncthreads();
    #pragma unroll
    for (int i = 0; i < 2; ++i) {
        int cid = tid + i * 256;
        int c = cid >> 3, kc = cid & 7;
        u16x8 v;
        #pragma unroll
        for (int j = 0; j < 8; ++j) v[j] = f2bf(Wl[kc * 8 + j][c] * sc);
        *(u16x8*)(Wt + ((size_t)y * 64 + c) * 1024 + kt * 64 + ((kc ^ (c & 7)) * 8)) = v;
    }
}

__global__ __launch_bounds__(256)
void conv_wo(const float* __restrict__ Wo, unsigned short* __restrict__ Wot)
{
    __shared__ float Wl[64][65];
    const int tid = threadIdx.x;
    const int kt = blockIdx.x, ct = blockIdx.y;
    #pragma unroll
    for (int i = 0; i < 4; ++i) {
        int idx = tid + i * 256;
        int kk = idx >> 4, c4 = (idx & 15) * 4;
        *(float4*)&Wl[kk][c4] = *(const float4*)&Wo[(size_t)(kt * 64 + kk) * 1024 + ct * 64 + c4];
    }
    __syncthreads();
    #pragma unroll
    for (int i = 0; i < 2; ++i) {
        int cid = tid + i * 256;
        int c = cid >> 3, kc = cid & 7;
        u16x8 v;
        #pragma unroll
        for (int j = 0; j < 8; ++j) v[j] = f2bf(Wl[kc * 8 + j][c]);
        *(u16x8*)(Wot + (size_t)(ct * 64 + c) * 1024 + kt * 64 + ((kc ^ (c & 7)) * 8)) = v;
    }
}

// ------------------------------------------------------------ QKV MFMA GEMM
// K is stored with per-row XOR-chunk swizzle (chunk' = chunk ^ (s&7)) so attn
// can cp16-stage rows linearly and ds_read conflict-free.
// V is written TRANSPOSED [bh][d][s] with per-64-col-span chunk swizzle by d.
__global__ __launch_bounds__(256, 2)
void qkv_mfma(const unsigned short* __restrict__ Xs,
              const unsigned short* __restrict__ Wt,
              unsigned short* __restrict__ Qo,
              unsigned short* __restrict__ Ko,
              unsigned short* __restrict__ Vo)
{
    __shared__ __align__(16) unsigned short As[2][128 * 64];
    __shared__ __align__(16) unsigned short Bs[2][64 * 64];

    const int tid  = threadIdx.x;
    const int wid  = tid >> 6;
    const int lane = tid & 63;
    const int lg   = lane >> 4;
    const int lr   = lane & 15;
    const int row0 = blockIdx.x * 128;
    const int y    = blockIdx.y;
    const int mat  = y >> 4;
    const int h    = y & 15;

    const unsigned short* Wh = Wt + (size_t)y * (64 * 1024);
    unsigned short* Out = (mat == 0 ? Qo : (mat == 1 ? Ko : Vo)) + (size_t)h * S_ * DH_;

    const int sr = tid >> 3;
    const int sc = tid & 7;

    f32x4 acc[2][4];
    #pragma unroll
    for (int rb = 0; rb < 2; ++rb)
        #pragma unroll
        for (int nb = 0; nb < 4; ++nb) acc[rb][nb] = (f32x4)(0.f);

    #pragma unroll
    for (int i = 0; i < 4; ++i)
        cp16(Xs + (size_t)(row0 + sr + i * 32) * 1024 + sc * 8, &As[0][(tid + i * 256) * 8]);
    #pragma unroll
    for (int i = 0; i < 2; ++i)
        cp16(Wh + (size_t)(sr + i * 32) * 1024 + sc * 8, &Bs[0][(tid + i * 256) * 8]);
    asm volatile("s_waitcnt vmcnt(0)" ::: "memory");
    __syncthreads();

    int cur = 0;
    for (int kt = 0; kt < 16; ++kt) {
        if (kt < 15) {
            const int kb = (kt + 1) * 64;
            #pragma unroll
            for (int i = 0; i < 4; ++i)
                cp16(Xs + (size_t)(row0 + sr + i * 32) * 1024 + kb + sc * 8,
                     &As[cur ^ 1][(tid + i * 256) * 8]);
            #pragma unroll
            for (int i = 0; i < 2; ++i)
                cp16(Wh + (size_t)(sr + i * 32) * 1024 + kb + sc * 8,
                     &Bs[cur ^ 1][(tid + i * 256) * 8]);
        }
        bf16x8 af[2][2], bfr[4][2];
        #pragma unroll
        for (int c = 0; c < 2; ++c) {
            #pragma unroll
            for (int rb = 0; rb < 2; ++rb) {
                int row = wid * 32 + rb * 16 + lr;
                int chk = (c * 4 + lg) ^ (row & 7);
                af[rb][c] = *(const bf16x8*)&As[cur][row * 64 + chk * 8];
            }
            #pragma unroll
            for (int nb = 0; nb < 4; ++nb) {
                int brow = nb * 16 + lr;
                int chk = (c * 4 + lg) ^ (brow & 7);
                bfr[nb][c] = *(const bf16x8*)&Bs[cur][brow * 64 + chk * 8];
            }
        }
        #pragma unroll
        for (int c = 0; c < 2; ++c)
            #pragma unroll
            for (int nb = 0; nb < 4; ++nb)
                #pragma unroll
                for (int rb = 0; rb < 2; ++rb)
                    acc[rb][nb] = __builtin_amdgcn_mfma_f32_16x16x32_bf16(
                        af[rb][c], bfr[nb][c], acc[rb][nb], 0, 0, 0);
        asm volatile("s_waitcnt vmcnt(0)" ::: "memory");
        __syncthreads();
        cur ^= 1;
    }

    if (mat == 2) {
        // transpose 128s x 64d -> V^T [bh][d][s] via LDS (reuse As, pitch 132)
        unsigned short* T = (unsigned short*)&As[0][0];
        #pragma unroll
        for (int rb = 0; rb < 2; ++rb)
            #pragma unroll
            for (int r = 0; r < 4; ++r) {
                int sl = wid * 32 + rb * 16 + lg * 4 + r;
                #pragma unroll
                for (int nb = 0; nb < 4; ++nb)
                    T[(nb * 16 + lr) * 132 + sl] = f2bf(acc[rb][nb][r]);
            }
        __syncthreads();
        const int bb = row0 >> 11;
        const int s0 = row0 & (S_ - 1);
        unsigned short* OutT = Vo + ((size_t)bb * H_ + h) * DH_ * S_;
        int d = tid >> 2, s4 = (tid & 3) * 32;
        #pragma unroll
        for (int i = 0; i < 4; ++i) {
            int p  = s4 + i * 8;                         // 0..120, chunk-aligned
            int ps = (p & 64) | ((((p >> 3) & 7) ^ (d & 7)) << 3);  // XOR swizzle per 64-span
            u16x8 v = *(const u16x8*)&T[d * 132 + p];
            *(u16x8*)(OutT + (size_t)d * S_ + s0 + ps) = v;
        }
    } else {
        #pragma unroll
        for (int rb = 0; rb < 2; ++rb)
            #pragma unroll
            for (int r = 0; r < 4; ++r) {
                int row = row0 + wid * 32 + rb * 16 + lg * 4 + r;
                int b = row >> 11, s = row & (S_ - 1);
                size_t base = (size_t)b * H_ * S_ * DH_ + (size_t)s * DH_;
                #pragma unroll
                for (int nb = 0; nb < 4; ++nb) {
                    int cc  = nb * 16 + lr;
                    int col = (mat == 1) ? (((((cc >> 3) ^ (s & 7)) << 3)) | (cc & 7)) : cc;
                    Out[base + col] = f2bf(acc[rb][nb][r]);
                }
            }
    }
}

// --------------------------------------------- flash attention, LDS dbuf
// 4 waves/block, lane owns q-row (lane&31). KV tile 64 keys, staged ONCE per
// block into LDS via global_load_lds double-buffer (1 barrier/tile). K and
// V^T global storage is pre-swizzled, so linear cp16 + XOR ds_read is
// conflict-free. Softmax lane-local (swapped QK^T); P packed in-reg.
__global__ __launch_bounds__(256, 2)
void attn_kernel(const unsigned short* __restrict__ Q,
                 const unsigned short* __restrict__ K,
                 const unsigned short* __restrict__ Vt,   // [bh][64 d][2048 s]
                 unsigned short* __restrict__ Cs)
{
    __shared__ __align__(16) unsigned short SH[2][2][64 * 64];  // [buf][K|V][64x64]

    const int tid  = threadIdx.x;
    const int wid  = tid >> 6;
    const int lane = tid & 63;
    const int h    = lane >> 5;     // lane half
    const int q31  = lane & 31;     // this lane's q-row
    // XCD-chunked decode: all 16 q-blocks of one bh share id%8 -> same XCD
    const int id   = blockIdx.x;          // 0..1023
    const int bh   = (id & 7) * 8 + (id >> 7);
    const int qx   = (id >> 3) & 15;
    const int b    = bh >> 4;
    const int hh   = bh & 15;
    const int q0   = qx * 128;
    const int qrow = q0 + wid * 32 + q31;

    const unsigned short* Qbh = Q  + (size_t)bh * S_ * DH_;
    const unsigned short* Kbh = K  + (size_t)bh * S_ * DH_;
    const unsigned short* Vbh = Vt + (size_t)bh * DH_ * S_;

    bf16x8 qf[4];
    #pragma unroll
    for (int dc = 0; dc < 4; ++dc)
        qf[dc] = *(const bf16x8*)(Qbh + (size_t)qrow * DH_ + dc * 16 + h * 8);

    f32x16 oacc[2];
    oacc[0] = (f32x16)0.f;
    oacc[1] = (f32x16)0.f;
    float m = -1e30f, lsum = 0.f;

    const int strow = tid >> 3;     // staging row base (+p*32)
    const int stchk = tid & 7;      // staging 16B chunk

    auto STAGE = [&](int bi, int kt) {
        #pragma unroll
        for (int p = 0; p < 2; ++p)   // K tile rows (swizzled in global)
            cp16(Kbh + (size_t)(kt * 64 + strow + p * 32) * DH_ + stchk * 8,
                 &SH[bi][0][(strow + p * 32) * 64 + stchk * 8]);
        #pragma unroll
        for (int p = 0; p < 2; ++p)   // V^T d-rows, 64-col slice (swizzled)
            cp16(Vbh + (size_t)(strow + p * 32) * S_ + kt * 64 + stchk * 8,
                 &SH[bi][1][(strow + p * 32) * 64 + stchk * 8]);
    };

    STAGE(0, 0);
    __syncthreads();                 // drains vmcnt before barrier

    int cur = 0;
    const int swb = q31 & 7;
    for (int kt = 0; kt < S_ / 64; ++kt) {
        if (kt < S_ / 64 - 1) STAGE(cur ^ 1, kt + 1);
        const unsigned short* Kl = &SH[cur][0][0];
        const unsigned short* Vl = &SH[cur][1][0];

        // ---- S^T = K Q^T: D rows = key, cols = q (lane&31) ----
        f32x16 sf[2];
        #pragma unroll
        for (int kb = 0; kb < 2; ++kb) {
            f32x16 s = (f32x16)0.f;
            #pragma unroll
            for (int dc = 0; dc < 4; ++dc) {
                bf16x8 kf = *(const bf16x8*)&Kl[(kb * 32 + q31) * 64 + ((dc * 2 + h) ^ swb) * 8];
                s = __builtin_amdgcn_mfma_f32_32x32x16_bf16(kf, qf[dc], s, 0, 0, 0);
            }
            sf[kb] = s;
        }

        // ---- lane-local online softmax (exp2 domain; defer-max THR=8) ----
        float mx = -1e30f;
        #pragma unroll
        for (int kb = 0; kb < 2; ++kb)
            #pragma unroll
            for (int r = 0; r < 16; r += 4)
                mx = fmaxf(mx, fmaxf(fmaxf(sf[kb][r], sf[kb][r + 1]),
                                     fmaxf(sf[kb][r + 2], sf[kb][r + 3])));
        mx = fmaxf(mx, __shfl_xor(mx, 32));
        if (!__all(mx <= m + 8.f)) {
            float mnew = fmaxf(m, mx);
            float a = fexp2(m - mnew);
            m = mnew;
            lsum *= a;
            oacc[0] *= a;
            oacc[1] *= a;
        }
        float p0 = 0.f, p1 = 0.f, p2 = 0.f, p3 = 0.f;
        #pragma unroll
        for (int kb = 0; kb < 2; ++kb)
            #pragma unroll
            for (int r = 0; r < 16; r += 4) {
                float e0 = fexp2(sf[kb][r]     - m);
                float e1 = fexp2(sf[kb][r + 1] - m);
                float e2 = fexp2(sf[kb][r + 2] - m);
                float e3 = fexp2(sf[kb][r + 3] - m);
                sf[kb][r] = e0; sf[kb][r + 1] = e1; sf[kb][r + 2] = e2; sf[kb][r + 3] = e3;
                p0 += e0; p1 += e1; p2 += e2; p3 += e3;
            }
        float ps = (p0 + p1) + (p2 + p3);
        ps += __shfl_xor(ps, 32);
        lsum += ps;

        // ---- pack P to bf16 pairs; exchange lane halves ----
        unsigned int own[2][8], swp[2][8];
        #pragma unroll
        for (int kb = 0; kb < 2; ++kb)
            #pragma unroll
            for (int j = 0; j < 8; ++j)
                own[kb][j] = cvtpk(sf[kb][2 * j], sf[kb][2 * j + 1]);
        #pragma unroll
        for (int kb = 0; kb < 2; ++kb)
            #pragma unroll
            for (int j = 0; j < 8; ++j)
                swp[kb][j] = (unsigned int)__shfl_xor((int)own[kb][j], 32);

        // ---- O^T += V^T P^T: D rows = d, cols = q ----
        #pragma unroll
        for (int kB = 0; kB < 4; ++kB) {
            const int kb = kB >> 1;
            const int J  = (kB & 1) * 4;
            unsigned int b0 = h ? swp[kb][J + 2] : own[kb][J + 0];
            unsigned int b1 = h ? swp[kb][J + 3] : own[kb][J + 1];
            unsigned int b2 = h ? own[kb][J + 2] : swp[kb][J + 0];
            unsigned int b3 = h ? own[kb][J + 3] : swp[kb][J + 1];
            u32x4 pw = {b0, b1, b2, b3};
            bf16x8 pb = __builtin_bit_cast(bf16x8, pw);
            #pragma unroll
            for (int dh = 0; dh < 2; ++dh) {
                bf16x8 vf = *(const bf16x8*)&Vl[(dh * 32 + q31) * 64 + ((kB * 2 + h) ^ swb) * 8];
                oacc[dh] = __builtin_amdgcn_mfma_f32_32x32x16_bf16(vf, pb, oacc[dh], 0, 0, 0);
            }
        }
        __syncthreads();             // drains staging vmcnt; all reads of cur done
        cur ^= 1;
    }

    // ---- epilogue: normalize, transpose via LDS (alias SH), swizzled stores ----
    unsigned short* Olds = &SH[0][0][0];     // 9216 elems needed, 16384 available
    float inv = 1.f / lsum;
    #pragma unroll
    for (int dh = 0; dh < 2; ++dh)
        #pragma unroll
        for (int r = 0; r < 16; ++r) {
            int d = dh * 32 + (r & 3) + ((r >> 2) << 3) + h * 4;
            Olds[wid * (32 * 72) + q31 * 72 + d] = f2bf(oacc[dh][r] * inv);
        }
    __syncthreads();
    const int orow = lane >> 1;
    const int srow = q0 + wid * 32 + orow;
    unsigned short* gout = Cs + ((size_t)b * S_ + srow) * 1024 + hh * 64;
    #pragma unroll
    for (int c = 0; c < 4; ++c) {
        int ch  = (lane & 1) * 4 + c;
        int chs = ch ^ (srow & 7);
        u16x8 v = *(const u16x8*)&Olds[wid * (32 * 72) + orow * 72 + ch * 8];
        *(u16x8*)(gout + chs * 8) = v;
    }
}

// ---------------------------------------------------------- output proj MFMA
__global__ __launch_bounds__(256, 2)
void oproj_mfma(const unsigned short* __restrict__ Cs,
                const unsigned short* __restrict__ Wot,
                const float* __restrict__ bo,
                float* __restrict__ out)
{
    __shared__ __align__(16) unsigned short As[2][128 * 64];
    __shared__ __align__(16) unsigned short Bs[2][64 * 64];

    const int tid  = threadIdx.x;
    const int wid  = tid >> 6;
    const int lane = tid & 63;
    const int lg   = lane >> 4;
    const int lr   = lane & 15;
    const int row0 = blockIdx.x * 128;
    const int col0 = blockIdx.y * 64;

    const int sr = tid >> 3;
    const int sc = tid & 7;

    f32x4 acc[2][4];
    #pragma unroll
    for (int rb = 0; rb < 2; ++rb)
        #pragma unroll
        for (int nb = 0; nb < 4; ++nb) acc[rb][nb] = (f32x4)(0.f);

    #pragma unroll
    for (int i = 0; i < 4; ++i)
        cp16(Cs + (size_t)(row0 + sr + i * 32) * 1024 + sc * 8, &As[0][(tid + i * 256) * 8]);
    #pragma unroll
    for (int i = 0; i < 2; ++i)
        cp16(Wot + (size_t)(col0 + sr + i * 32) * 1024 + sc * 8, &Bs[0][(tid + i * 256) * 8]);
    asm volatile("s_waitcnt vmcnt(0)" ::: "memory");
    __syncthreads();

    int cur = 0;
    for (int kt = 0; kt < 16; ++kt) {
        if (kt < 15) {
            const int kb = (kt + 1) * 64;
            #pragma unroll
            for (int i = 0; i < 4; ++i)
                cp16(Cs + (size_t)(row0 + sr + i * 32) * 1024 + kb + sc * 8,
                     &As[cur ^ 1][(tid + i * 256) * 8]);
            #pragma unroll
            for (int i = 0; i < 2; ++i)
                cp16(Wot + (size_t)(col0 + sr + i * 32) * 1024 + kb + sc * 8,
                     &Bs[cur ^ 1][(tid + i * 256) * 8]);
        }
        bf16x8 af[2][2], bfr[4][2];
        #pragma unroll
        for (int c = 0; c < 2; ++c) {
            #pragma unroll
            for (int rb = 0; rb < 2; ++rb) {
                int row = wid * 32 + rb * 16 + lr;
                int chk = (c * 4 + lg) ^ (row & 7);
                af[rb][c] = *(const bf16x8*)&As[cur][row * 64 + chk * 8];
            }
            #pragma unroll
            for (int nb = 0; nb < 4; ++nb) {
                int brow = nb * 16 + lr;
                int chk = (c * 4 + lg) ^ (brow & 7);
                bfr[nb][c] = *(const bf16x8*)&Bs[cur][brow * 64 + chk * 8];
            }
        }
        #pragma unroll
        for (int c = 0; c < 2; ++c)
            #pragma unroll
            for (int nb = 0; nb < 4; ++nb)
                #pragma unroll
                for (int rb = 0; rb < 2; ++rb)
                    acc[rb][nb] = __builtin_amdgcn_mfma_f32_16x16x32_bf16(
                        af[rb][c], bfr[nb][c], acc[rb][nb], 0, 0, 0);
        asm volatile("s_waitcnt vmcnt(0)" ::: "memory");
        __syncthreads();
        cur ^= 1;
    }

    float bb[4];
    #pragma unroll
    for (int nb = 0; nb < 4; ++nb) bb[nb] = bo[col0 + nb * 16 + lr];
    #pragma unroll
    for (int rb = 0; rb < 2; ++rb)
        #pragma unroll
        for (int r = 0; r < 4; ++r) {
            int row = row0 + wid * 32 + rb * 16 + lg * 4 + r;
            #pragma unroll
            for (int nb = 0; nb < 4; ++nb)
                out[(size_t)row * 1024 + col0 + nb * 16 + lr] = acc[rb][nb][r] + bb[nb];
        }
}

extern "C" void kernel_launch(void* const* d_in, const int* in_sizes, int n_in,
                              void* d_out, int out_size, void* d_ws, size_t ws_size,
                              hipStream_t stream) {
    const float* x  = (const float*)d_in[0];
    const float* Wq = (const float*)d_in[1];
    const float* Wk = (const float*)d_in[2];
    const float* Wv = (const float*)d_in[3];
    const float* Wo = (const float*)d_in[4];
    const float* bo = (const float*)d_in[5];
    float* out = (float*)d_out;

    const size_t perQ = (size_t)B_ * H_ * S_ * DH_;
    unsigned short* xs  = (unsigned short*)d_ws;
    unsigned short* Wt  = xs + (size_t)8192 * 1024;
    unsigned short* Wot = Wt + (size_t)48 * 64 * 1024;
    unsigned short* Qb  = Wot + (size_t)1024 * 1024;
    unsigned short* Kb  = Qb + perQ;                       // K swizzled rows
    unsigned short* Vb  = Kb + perQ;                       // V^T [bh][64][2048] swizzled
    unsigned short* Cb  = Vb + perQ;

    conv_x<<<4096, 256, 0, stream>>>(x, xs);
    conv_wqkv<<<dim3(16, 48), 256, 0, stream>>>(Wq, Wk, Wv, Wt);
    conv_wo<<<dim3(16, 16), 256, 0, stream>>>(Wo, Wot);
    qkv_mfma<<<dim3(64, 48), 256, 0, stream>>>(xs, Wt, Qb, Kb, Vb);
    attn_kernel<<<1024, 256, 0, stream>>>(Qb, Kb, Vb, Cb);
    oproj_mfma<<<dim3(64, 16), 256, 0, stream>>>(Cb, Wot, bo, out);
}